// Round 2
// baseline (511.046 us; speedup 1.0000x reference)
//
#include <hip/hip_runtime.h>

// Problem constants
#define BB    8
#define NBB   1024
#define KK    9
#define CC    32
#define CMM   128
#define NTOT  (BB*NBB)        // 8192
#define MM    (NBB*KK)        // 9216 per batch
#define MS    16              // m-split ways
#define MR    (MM/MS)         // 576 m per split
#define NEG   0.01f
#define EPS   1e-5f

// Workspace layout (floats)
#define OFF_CONVW 0
#define SZ_CONVW  (NTOT*KK*CC)            // 2359296
#define OFF_QPOS  (OFF_CONVW + SZ_CONVW)
#define SZ_QPOS   (BB*MM*2)               // 147456
#define OFF_KWT   (OFF_QPOS + SZ_QPOS)
#define SZ_KWT    (KK*CC*CC)              // 9216
#define OFF_PART  (OFF_KWT + SZ_KWT)
#define SZ_ONE    (NTOT*CC)               // 262144
#define SZ_PART   (MS*SZ_ONE)             // 4194304
// x0/x/h0 alias dead partial slots (partials consumed by k_leaky_stats):
#define OFF_X0    (OFF_PART)              // slot 0 (safe: same-thread RAW)
#define OFF_X     (OFF_PART + SZ_ONE)     // slot 1 (written in k_mlp1)
#define OFF_H0    (OFF_PART + 2*SZ_ONE)   // slots 2..5 (NTOT*CMM = 4 slots)
#define OFF_S1    (OFF_PART + SZ_PART)    // 64 floats
#define OFF_S2    (OFF_S1 + 64)           // 256 floats

// ---------------------------------------------------------------------------
// k_prep: qpos[b][m][d] = pos[b*NBB + m/9][d] + kpos[m%9][d]
//         kwT[k][c][cp] = kw[k][cp][c]
// ---------------------------------------------------------------------------
__global__ __launch_bounds__(256) void k_prep(const float* __restrict__ pos,
                                              const float* __restrict__ kpos,
                                              const float* __restrict__ kw,
                                              float* __restrict__ qpos,
                                              float* __restrict__ kwT) {
    int gid = blockIdx.x*256 + threadIdx.x;
    if (gid < BB*MM*2) {
        int b = gid / (MM*2);
        int r = gid - b*(MM*2);
        int m = r >> 1, d = r & 1;
        int np = m / 9, k9 = m - np*9;
        qpos[gid] = pos[((size_t)b*NBB + np)*2 + d] + kpos[k9*2 + d];
    } else {
        int i = gid - BB*MM*2;
        if (i < KK*CC*CC) {
            int k = i >> 10;
            int c = (i >> 5) & 31;
            int cp = i & 31;
            kwT[i] = kw[(k*CC + cp)*CC + c];
        }
    }
}

// ---------------------------------------------------------------------------
// k_convw: conv_w[n][k][c] = sum_cp w[n][cp] * kwT[k][c][cp]
// lane = n (weights row in VGPRs), kwT rows wave-uniform -> s_load.
// grid = 32 n-blocks x 9 k
// ---------------------------------------------------------------------------
__global__ __launch_bounds__(256) void k_convw(const float* __restrict__ w,
                                               const float* __restrict__ kwT,
                                               float* __restrict__ convw) {
    int nb = blockIdx.x / 9, k = blockIdx.x - nb*9;
    int n = nb*256 + threadIdx.x;
    float wv[32];
    #pragma unroll
    for (int q = 0; q < 8; ++q)
        *(float4*)&wv[q*4] = *(const float4*)&w[(size_t)n*CC + q*4];
    const float* kt = kwT + k*CC*CC;   // [c][cp], wave-uniform
    float res[32];
    #pragma unroll 4
    for (int c = 0; c < 32; ++c) {
        float a = 0.f;
        #pragma unroll
        for (int cp = 0; cp < 32; ++cp)
            a = fmaf(wv[cp], kt[c*32 + cp], a);
        res[c] = a;
    }
    float* dst = convw + ((size_t)n*KK + k)*CC;
    #pragma unroll
    for (int c = 0; c < 32; c += 4)
        *(float4*)&dst[c] = make_float4(res[c], res[c+1], res[c+2], res[c+3]);
}

// ---------------------------------------------------------------------------
// k_sample (dominant): part[ms][n][c] = sum_{m in slice}
//      exp(-2*|p_n - qpos_m|^2) * conv_w[m][c]
// lane = n. qpos/conv_w wave-uniform -> s_load; e per-lane in regs. NO LDS.
// grid = 32 row-blocks x 16 m-splits
// ---------------------------------------------------------------------------
__global__ __launch_bounds__(256) void k_sample(const float* __restrict__ pos,
                                                const float* __restrict__ qpos,
                                                const float* __restrict__ convw,
                                                float* __restrict__ part) {
    int blk = blockIdx.x;
    int rb = blk >> 4, ms = blk & 15;
    int n = rb*256 + threadIdx.x;
    int b = n >> 10;
    float2 p = *(const float2*)&pos[(size_t)n*2];
    float acc[32];
    #pragma unroll
    for (int c = 0; c < 32; ++c) acc[c] = 0.f;
    const float* qp = qpos + (size_t)(b*MM + ms*MR)*2;   // wave-uniform
    const float* wp = convw + (size_t)(b*MM + ms*MR)*CC; // wave-uniform
    const float L2 = -2.885390081777927f;  // -2*log2(e)
    #pragma unroll 2
    for (int i = 0; i < MR; ++i) {
        float qx = qp[2*i], qy = qp[2*i+1];
        float dx = p.x - qx, dy = p.y - qy;
        float d2 = fmaf(dx, dx, dy*dy);
        float e = exp2f(L2 * d2);
        #pragma unroll
        for (int c = 0; c < 32; ++c)
            acc[c] = fmaf(e, wp[32*i + c], acc[c]);
    }
    float* dst = part + (size_t)ms*SZ_ONE + (size_t)n*CC;
    #pragma unroll
    for (int c = 0; c < 32; c += 4)
        *(float4*)&dst[c] = make_float4(acc[c], acc[c+1], acc[c+2], acc[c+3]);
}

// ---------------------------------------------------------------------------
// k_leaky_stats: x0 = leaky(sum of 16 partials); accumulate bn1 sum/sumsq
// ---------------------------------------------------------------------------
__global__ __launch_bounds__(256) void k_leaky_stats(const float* __restrict__ part,
                                                     float* __restrict__ x0,
                                                     float* __restrict__ s1) {
    __shared__ float ss[32], sq[32];
    int t = threadIdx.x;
    if (t < 32) { ss[t] = 0.f; sq[t] = 0.f; }
    __syncthreads();
    float lsum = 0.f, lsq = 0.f;
    int base = blockIdx.x * 2048;
    for (int j = 0; j < 8; ++j) {
        int idx = base + j*256 + t;
        float v = 0.f;
        #pragma unroll
        for (int s = 0; s < MS; ++s) v += part[(size_t)s*SZ_ONE + idx];
        v = v >= 0.f ? v : NEG*v;
        x0[idx] = v;   // x0 aliases partial slot 0: same-thread read-then-write
        lsum += v; lsq = fmaf(v, v, lsq);
    }
    atomicAdd(&ss[t & 31], lsum);
    atomicAdd(&sq[t & 31], lsq);
    __syncthreads();
    if (t < 32) { atomicAdd(&s1[t], ss[t]); atomicAdd(&s1[32+t], sq[t]); }
}

// ---------------------------------------------------------------------------
// k_mlp1: x = bn1(x0) + weights (store); h0 = leaky(x @ W1 + b1) (store)
// lane = n (64 rows/block); 4 waves = 4 j-quarters; W1 rows via s_load.
// grid = 128
// ---------------------------------------------------------------------------
__global__ __launch_bounds__(256) void k_mlp1(const float* __restrict__ x0,
                                              const float* __restrict__ wts,
                                              const float* __restrict__ gma,
                                              const float* __restrict__ bta,
                                              const float* __restrict__ W1,
                                              const float* __restrict__ b1,
                                              const float* __restrict__ s1,
                                              float* __restrict__ x,
                                              float* __restrict__ h0) {
    int t = threadIdx.x;
    int lane = t & 63, w = t >> 6;
    int n = blockIdx.x*64 + lane;
    int j0 = w*32;
    float xv[32];
    #pragma unroll
    for (int c = 0; c < 32; ++c) {
        float mu  = s1[c] * (1.f/NTOT);
        float var = s1[32+c]*(1.f/NTOT) - mu*mu;
        float a   = gma[c] * rsqrtf(var + EPS);
        float v   = x0[(size_t)n*CC + c];
        xv[c] = a*(v - mu) + bta[c] + wts[(size_t)n*CC + c];
    }
    if (w == 0) {   // store x once
        #pragma unroll
        for (int c = 0; c < 32; c += 4)
            *(float4*)&x[(size_t)n*CC + c] = make_float4(xv[c], xv[c+1], xv[c+2], xv[c+3]);
    }
    float acc[32];
    #pragma unroll
    for (int jj = 0; jj < 32; ++jj) acc[jj] = b1[j0 + jj];
    #pragma unroll 2
    for (int c = 0; c < 32; ++c) {
        float xc = xv[c];
        const float* w1r = W1 + c*CMM + j0;   // wave-uniform -> s_load
        #pragma unroll
        for (int jj = 0; jj < 32; ++jj)
            acc[jj] = fmaf(xc, w1r[jj], acc[jj]);
    }
    float* hd = h0 + (size_t)n*CMM + j0;
    #pragma unroll
    for (int jj = 0; jj < 32; jj += 4) {
        float4 v;
        v.x = acc[jj]   >= 0.f ? acc[jj]   : NEG*acc[jj];
        v.y = acc[jj+1] >= 0.f ? acc[jj+1] : NEG*acc[jj+1];
        v.z = acc[jj+2] >= 0.f ? acc[jj+2] : NEG*acc[jj+2];
        v.w = acc[jj+3] >= 0.f ? acc[jj+3] : NEG*acc[jj+3];
        *(float4*)&hd[jj] = v;
    }
}

// ---------------------------------------------------------------------------
// k_stats2: per-channel sum/sumsq of h0 for bn2
// ---------------------------------------------------------------------------
__global__ __launch_bounds__(256) void k_stats2(const float* __restrict__ h0,
                                                float* __restrict__ s2) {
    __shared__ float ss[128], sq[128];
    int t = threadIdx.x;
    if (t < 128) { ss[t] = 0.f; sq[t] = 0.f; }
    __syncthreads();
    float lsum = 0.f, lsq = 0.f;
    int base = blockIdx.x * 4096;
    for (int i = 0; i < 16; ++i) {
        float v = h0[base + i*256 + t];
        lsum += v; lsq = fmaf(v, v, lsq);
    }
    int j = t & 127;
    atomicAdd(&ss[j], lsum);
    atomicAdd(&sq[j], lsq);
    __syncthreads();
    if (t < 128) { atomicAdd(&s2[t], ss[t]); atomicAdd(&s2[128+t], sq[t]); }
}

// ---------------------------------------------------------------------------
// k_mlp2: h = bn2(h0); mlp = h @ W2 + b2; out0 = pos + mlp[:,:2];
//         out1 = x + mlp[:,2:]. lane = n; 4 waves = j-quarters; LDS reduce.
// grid = 128
// ---------------------------------------------------------------------------
__global__ __launch_bounds__(256) void k_mlp2(const float* __restrict__ h0,
                                              const float* __restrict__ x,
                                              const float* __restrict__ pos,
                                              const float* __restrict__ g2,
                                              const float* __restrict__ bt2,
                                              const float* __restrict__ W2,
                                              const float* __restrict__ b2,
                                              const float* __restrict__ s2,
                                              float* __restrict__ out) {
    __shared__ float red[4][64][34];
    int t = threadIdx.x;
    int lane = t & 63, w = t >> 6;
    int n = blockIdx.x*64 + lane;
    int j0 = w*32;
    float hv[32];
    #pragma unroll
    for (int q = 0; q < 8; ++q)
        *(float4*)&hv[q*4] = *(const float4*)&h0[(size_t)n*CMM + j0 + q*4];
    #pragma unroll
    for (int jj = 0; jj < 32; ++jj) {
        int j = j0 + jj;
        float mu  = s2[j] * (1.f/NTOT);
        float var = s2[128+j]*(1.f/NTOT) - mu*mu;
        float a   = g2[j] * rsqrtf(var + EPS);
        hv[jj] = a*(hv[jj] - mu) + bt2[j];
    }
    float acc[34];
    #pragma unroll
    for (int c = 0; c < 34; ++c) acc[c] = 0.f;
    for (int jj = 0; jj < 32; ++jj) {
        float h = hv[jj];
        const float* w2r = W2 + (size_t)(j0 + jj)*34;   // wave-uniform -> s_load
        #pragma unroll
        for (int c = 0; c < 34; ++c)
            acc[c] = fmaf(h, w2r[c], acc[c]);
    }
    #pragma unroll
    for (int c = 0; c < 34; ++c) red[w][lane][c] = acc[c];
    __syncthreads();
    int r = t & 63, seg = t >> 6;
    int c0 = seg*9, c1 = c0 + 9 < 34 ? c0 + 9 : 34;
    int nn = blockIdx.x*64 + r;
    for (int c = c0; c < c1; ++c) {
        float v = red[0][r][c] + red[1][r][c] + red[2][r][c] + red[3][r][c] + b2[c];
        if (c < 2)
            out[(size_t)nn*2 + c] = pos[(size_t)nn*2 + c] + v;
        else
            out[16384 + (size_t)nn*32 + (c-2)] = x[(size_t)nn*32 + (c-2)] + v;
    }
}

// ---------------------------------------------------------------------------
extern "C" void kernel_launch(void* const* d_in, const int* in_sizes, int n_in,
                              void* d_out, int out_size, void* d_ws, size_t ws_size,
                              hipStream_t stream) {
    const float* positions = (const float*)d_in[0];
    const float* weights   = (const float*)d_in[1];
    // d_in[2] = batch (int32, all NB) — unused, shapes are static
    const float* kpos = (const float*)d_in[3];
    const float* kw   = (const float*)d_in[4];
    const float* cg   = (const float*)d_in[5];
    const float* cb   = (const float*)d_in[6];
    const float* W1   = (const float*)d_in[7];
    const float* b1   = (const float*)d_in[8];
    const float* bg   = (const float*)d_in[9];
    const float* bb   = (const float*)d_in[10];
    const float* W2   = (const float*)d_in[11];
    const float* b2   = (const float*)d_in[12];
    float* ws  = (float*)d_ws;
    float* out = (float*)d_out;

    hipMemsetAsync(ws + OFF_S1, 0, (64 + 256)*sizeof(float), stream);

    k_prep<<<612, 256, 0, stream>>>(positions, kpos, kw, ws + OFF_QPOS, ws + OFF_KWT);
    k_convw<<<288, 256, 0, stream>>>(weights, ws + OFF_KWT, ws + OFF_CONVW);
    k_sample<<<512, 256, 0, stream>>>(positions, ws + OFF_QPOS, ws + OFF_CONVW, ws + OFF_PART);
    k_leaky_stats<<<128, 256, 0, stream>>>(ws + OFF_PART, ws + OFF_X0, ws + OFF_S1);
    k_mlp1<<<128, 256, 0, stream>>>(ws + OFF_X0, weights, cg, cb, W1, b1,
                                    ws + OFF_S1, ws + OFF_X, ws + OFF_H0);
    k_stats2<<<256, 256, 0, stream>>>(ws + OFF_H0, ws + OFF_S2);
    k_mlp2<<<128, 256, 0, stream>>>(ws + OFF_H0, ws + OFF_X, positions,
                                    bg, bb, W2, b2, ws + OFF_S2, out);
}

// Round 3
// 206.108 us; speedup vs baseline: 2.4795x; 2.4795x over previous
//
#include <hip/hip_runtime.h>
#include <hip/hip_bf16.h>

// Problem constants
#define BB    8
#define NBB   1024
#define KK    9
#define CC    32
#define CMM   128
#define NTOT  (BB*NBB)        // 8192
#define MM    (NBB*KK)        // 9216 per batch
#define MS    16              // K-split ways
#define MR    (MM/MS)         // 576 m per split
#define NEG   0.01f
#define EPS   1e-5f

#define L2C   (-2.8853900817779268f)   /* -2*log2(e) */

// Workspace layout (floats)
#define OFF_CWT   0
#define SZ_CWT    (BB*CC*MM/2)            // bf16: 1179648 floats
#define OFF_CFX   (OFF_CWT + SZ_CWT)
#define OFF_CFY   (OFF_CFX + BB*MM)
#define OFF_CF0   (OFF_CFY + BB*MM)
#define OFF_KWT   (OFF_CF0 + BB*MM)
#define OFF_PART  (OFF_KWT + KK*CC*CC)
#define SZ_ONE    (NTOT*CC)               // 262144
#define SZ_PART   (MS*SZ_ONE)
// aliases into dead partial slots (consumed by k_leaky_stats before reuse)
#define OFF_X0    (OFF_PART)              // slot 0 (same-thread RAW in k_leaky)
#define OFF_X     (OFF_PART + SZ_ONE)     // slot 1
#define OFF_H0    (OFF_PART + 2*SZ_ONE)   // slots 2..5
#define OFF_S1    (OFF_PART + SZ_PART)    // 64 floats
#define OFF_S2    (OFF_S1 + 64)           // 256 floats

typedef __attribute__((ext_vector_type(8))) short short8;
typedef __attribute__((ext_vector_type(4))) float f32x4;

static __device__ __forceinline__ unsigned short f2bf_rne(float f) {
    __hip_bfloat16 h = __float2bfloat16(f);
    return *reinterpret_cast<unsigned short*>(&h);
}

// ---------------------------------------------------------------------------
// k_prep: per-m Gaussian coefs + kw transpose.
//   q = pos[m/9] + kpos[m%9]
//   cfx = -2*L2C*qx, cfy = -2*L2C*qy, cf0 = L2C*(qx^2+qy^2)
//   E(n,m) = cn + cf0 + cfx*px + cfy*py, e = exp2(E), cn = L2C*(px^2+py^2)
// ---------------------------------------------------------------------------
__global__ __launch_bounds__(256) void k_prep(const float* __restrict__ pos,
                                              const float* __restrict__ kpos,
                                              const float* __restrict__ kw,
                                              float* __restrict__ cfx,
                                              float* __restrict__ cfy,
                                              float* __restrict__ cf0,
                                              float* __restrict__ kwT) {
    int gid = blockIdx.x*256 + threadIdx.x;
    if (gid < BB*MM) {
        int b = gid / MM;
        int m = gid - b*MM;
        int np = m / 9, k9 = m - np*9;
        float qx = pos[((size_t)(b*NBB + np))*2 + 0] + kpos[k9*2 + 0];
        float qy = pos[((size_t)(b*NBB + np))*2 + 1] + kpos[k9*2 + 1];
        cfx[gid] = -2.f*L2C*qx;
        cfy[gid] = -2.f*L2C*qy;
        cf0[gid] = L2C*(qx*qx + qy*qy);
    } else {
        int i = gid - BB*MM;
        if (i < KK*CC*CC) {
            int k = i >> 10, c = (i >> 5) & 31, cp = i & 31;
            kwT[i] = kw[(k*CC + cp)*CC + c];
        }
    }
}

// ---------------------------------------------------------------------------
// k_convw: cwT[b][c][m] (bf16), m = n_loc*9+k, conv_w[n][k][c] = sum_cp w*kwT
// 64 n per block; lane = n; kwT rows via scalar loads; LDS transpose tile,
// coalesced bf16 writeout.
// ---------------------------------------------------------------------------
__global__ __launch_bounds__(256) void k_convw(const float* __restrict__ w,
                                               const float* __restrict__ kwT,
                                               short* __restrict__ cwT) {
    __shared__ unsigned short tile[32*576];   // 36 KB
    int t = threadIdx.x;
    int l = t & 63, wv = t >> 6;
    int blk = blockIdx.x;        // b*16 + nb
    int nb = blk & 15, b = blk >> 4;
    int n = b*NBB + nb*64 + l;
    float wreg[32];
    #pragma unroll
    for (int q = 0; q < 8; ++q)
        *(float4*)&wreg[q*4] = *(const float4*)&w[(size_t)n*CC + q*4];
    int kbeg = (wv == 0) ? 0 : (wv*2 + 1);
    int kend = kbeg + ((wv == 0) ? 3 : 2);
    for (int k = kbeg; k < kend; ++k) {
        const float* kt = kwT + k*CC*CC;   // wave-uniform -> s_load
        #pragma unroll 4
        for (int c = 0; c < 32; ++c) {
            float a = 0.f;
            #pragma unroll
            for (int cp = 0; cp < 32; ++cp)
                a = fmaf(wreg[cp], kt[c*32 + cp], a);
            tile[c*576 + l*9 + k] = f2bf_rne(a);
        }
    }
    __syncthreads();
    int c = t >> 3, u0 = t & 7;
    short* dst = cwT + ((size_t)(b*CC + c))*MM + nb*576;
    #pragma unroll
    for (int it = 0; it < 9; ++it) {
        int unit = it*8 + u0;
        short8 v = *(const short8*)&tile[c*576 + unit*8];
        *(short8*)&dst[unit*8] = v;
    }
}

// ---------------------------------------------------------------------------
// k_sample (dominant, MFMA): part[ks][n][c] = sum_{m in K-range}
//      exp2(E(n,m)) * conv_w[m][c]
// MFMA 16x16x32 bf16, orientation M=c, N=n, K=m.
// A = cwT (global, per-lane 16B contiguous, L1-shared across waves)
// B = e computed in registers (3 VALU + v_exp + pack per element). NO LDS.
// grid = 8 b x 4 nblk(256 n) x 16 ksplit = 512 blocks; wave = 4 ntiles.
// ---------------------------------------------------------------------------
__global__ __launch_bounds__(256) void k_sample(const float* __restrict__ pos,
                                                const float* __restrict__ cfx,
                                                const float* __restrict__ cfy,
                                                const float* __restrict__ cf0,
                                                const short* __restrict__ cwT,
                                                float* __restrict__ part) {
    int t = threadIdx.x;
    int l = t & 63, w = t >> 6;
    int blk = blockIdx.x;
    int ks = blk & 15, nb = (blk >> 4) & 3, b = blk >> 6;
    int lane15 = l & 15, quad = l >> 4;
    int nbase = b*NBB + nb*256 + w*64;

    float px[4], py[4], cn[4];
    #pragma unroll
    for (int nt = 0; nt < 4; ++nt) {
        int n = nbase + nt*16 + lane15;
        float x = pos[(size_t)n*2], y = pos[(size_t)n*2 + 1];
        px[nt] = x; py[nt] = y; cn[nt] = L2C*(x*x + y*y);
    }
    f32x4 acc[4][2];
    #pragma unroll
    for (int nt = 0; nt < 4; ++nt) { acc[nt][0] = (f32x4)0.f; acc[nt][1] = (f32x4)0.f; }

    const float* bx = cfx + (size_t)b*MM;
    const float* by = cfy + (size_t)b*MM;
    const float* b0 = cf0 + (size_t)b*MM;
    const short* ca0 = cwT + (size_t)b*CC*MM + (size_t)lane15*MM;
    const short* ca1 = ca0 + (size_t)16*MM;

    int m0 = ks*MR + quad*8;
    #pragma unroll 2
    for (int kk = 0; kk < MR/32; ++kk, m0 += 32) {
        short8 a0 = *(const short8*)&ca0[m0];
        short8 a1 = *(const short8*)&ca1[m0];
        f32x4 vx0 = *(const f32x4*)&bx[m0];
        f32x4 vx1 = *(const f32x4*)&bx[m0 + 4];
        f32x4 vy0 = *(const f32x4*)&by[m0];
        f32x4 vy1 = *(const f32x4*)&by[m0 + 4];
        f32x4 v00 = *(const f32x4*)&b0[m0];
        f32x4 v01 = *(const f32x4*)&b0[m0 + 4];
        #pragma unroll
        for (int nt = 0; nt < 4; ++nt) {
            float X = px[nt], Y = py[nt], C = cn[nt];
            float e0 = __builtin_amdgcn_exp2f(fmaf(vx0.x, X, fmaf(vy0.x, Y, v00.x + C)));
            float e1 = __builtin_amdgcn_exp2f(fmaf(vx0.y, X, fmaf(vy0.y, Y, v00.y + C)));
            float e2 = __builtin_amdgcn_exp2f(fmaf(vx0.z, X, fmaf(vy0.z, Y, v00.z + C)));
            float e3 = __builtin_amdgcn_exp2f(fmaf(vx0.w, X, fmaf(vy0.w, Y, v00.w + C)));
            float e4 = __builtin_amdgcn_exp2f(fmaf(vx1.x, X, fmaf(vy1.x, Y, v01.x + C)));
            float e5 = __builtin_amdgcn_exp2f(fmaf(vx1.y, X, fmaf(vy1.y, Y, v01.y + C)));
            float e6 = __builtin_amdgcn_exp2f(fmaf(vx1.z, X, fmaf(vy1.z, Y, v01.z + C)));
            float e7 = __builtin_amdgcn_exp2f(fmaf(vx1.w, X, fmaf(vy1.w, Y, v01.w + C)));
            union { unsigned int u[4]; short8 s; } bf;
            bf.u[0] = (__float_as_uint(e0) >> 16) | (__float_as_uint(e1) & 0xffff0000u);
            bf.u[1] = (__float_as_uint(e2) >> 16) | (__float_as_uint(e3) & 0xffff0000u);
            bf.u[2] = (__float_as_uint(e4) >> 16) | (__float_as_uint(e5) & 0xffff0000u);
            bf.u[3] = (__float_as_uint(e6) >> 16) | (__float_as_uint(e7) & 0xffff0000u);
            acc[nt][0] = __builtin_amdgcn_mfma_f32_16x16x32_bf16(a0, bf.s, acc[nt][0], 0, 0, 0);
            acc[nt][1] = __builtin_amdgcn_mfma_f32_16x16x32_bf16(a1, bf.s, acc[nt][1], 0, 0, 0);
        }
    }
    // D layout: col(n) = lane&15, row(c) = quad*4 + reg
    #pragma unroll
    for (int nt = 0; nt < 4; ++nt) {
        int n = nbase + nt*16 + lane15;
        #pragma unroll
        for (int ct = 0; ct < 2; ++ct) {
            int c = ct*16 + quad*4;
            *(f32x4*)&part[((size_t)ks*NTOT + n)*CC + c] = acc[nt][ct];
        }
    }
}

// ---------------------------------------------------------------------------
// k_leaky_stats: x0 = leaky(sum of 16 partials); accumulate bn1 sum/sumsq
// ---------------------------------------------------------------------------
__global__ __launch_bounds__(256) void k_leaky_stats(const float* __restrict__ part,
                                                     float* __restrict__ x0,
                                                     float* __restrict__ s1) {
    __shared__ float ss[32], sq[32];
    int t = threadIdx.x;
    if (t < 32) { ss[t] = 0.f; sq[t] = 0.f; }
    __syncthreads();
    float lsum = 0.f, lsq = 0.f;
    int base = blockIdx.x * 2048;
    for (int j = 0; j < 8; ++j) {
        int idx = base + j*256 + t;
        float v = 0.f;
        #pragma unroll
        for (int s = 0; s < MS; ++s) v += part[(size_t)s*SZ_ONE + idx];
        v = v >= 0.f ? v : NEG*v;
        x0[idx] = v;   // aliases partial slot 0: same-thread read-then-write
        lsum += v; lsq = fmaf(v, v, lsq);
    }
    atomicAdd(&ss[t & 31], lsum);
    atomicAdd(&sq[t & 31], lsq);
    __syncthreads();
    if (t < 32) { atomicAdd(&s1[t], ss[t]); atomicAdd(&s1[32+t], sq[t]); }
}

// ---------------------------------------------------------------------------
// k_mlp1: x = bn1(x0) + weights; h0 = leaky(x @ W1 + b1)
// ---------------------------------------------------------------------------
__global__ __launch_bounds__(256) void k_mlp1(const float* __restrict__ x0,
                                              const float* __restrict__ wts,
                                              const float* __restrict__ gma,
                                              const float* __restrict__ bta,
                                              const float* __restrict__ W1,
                                              const float* __restrict__ b1,
                                              const float* __restrict__ s1,
                                              float* __restrict__ x,
                                              float* __restrict__ h0) {
    int t = threadIdx.x;
    int lane = t & 63, w = t >> 6;
    int n = blockIdx.x*64 + lane;
    int j0 = w*32;
    float xv[32];
    #pragma unroll
    for (int c = 0; c < 32; ++c) {
        float mu  = s1[c] * (1.f/NTOT);
        float var = s1[32+c]*(1.f/NTOT) - mu*mu;
        float a   = gma[c] * rsqrtf(var + EPS);
        float v   = x0[(size_t)n*CC + c];
        xv[c] = a*(v - mu) + bta[c] + wts[(size_t)n*CC + c];
    }
    if (w == 0) {
        #pragma unroll
        for (int c = 0; c < 32; c += 4)
            *(float4*)&x[(size_t)n*CC + c] = make_float4(xv[c], xv[c+1], xv[c+2], xv[c+3]);
    }
    float acc[32];
    #pragma unroll
    for (int jj = 0; jj < 32; ++jj) acc[jj] = b1[j0 + jj];
    #pragma unroll 2
    for (int c = 0; c < 32; ++c) {
        float xc = xv[c];
        const float* w1r = W1 + c*CMM + j0;   // wave-uniform -> s_load
        #pragma unroll
        for (int jj = 0; jj < 32; ++jj)
            acc[jj] = fmaf(xc, w1r[jj], acc[jj]);
    }
    float* hd = h0 + (size_t)n*CMM + j0;
    #pragma unroll
    for (int jj = 0; jj < 32; jj += 4) {
        float4 v;
        v.x = acc[jj]   >= 0.f ? acc[jj]   : NEG*acc[jj];
        v.y = acc[jj+1] >= 0.f ? acc[jj+1] : NEG*acc[jj+1];
        v.z = acc[jj+2] >= 0.f ? acc[jj+2] : NEG*acc[jj+2];
        v.w = acc[jj+3] >= 0.f ? acc[jj+3] : NEG*acc[jj+3];
        *(float4*)&hd[jj] = v;
    }
}

// ---------------------------------------------------------------------------
// k_stats2: per-channel sum/sumsq of h0 for bn2
// ---------------------------------------------------------------------------
__global__ __launch_bounds__(256) void k_stats2(const float* __restrict__ h0,
                                                float* __restrict__ s2) {
    __shared__ float ss[128], sq[128];
    int t = threadIdx.x;
    if (t < 128) { ss[t] = 0.f; sq[t] = 0.f; }
    __syncthreads();
    float lsum = 0.f, lsq = 0.f;
    int base = blockIdx.x * 4096;
    for (int i = 0; i < 16; ++i) {
        float v = h0[base + i*256 + t];
        lsum += v; lsq = fmaf(v, v, lsq);
    }
    int j = t & 127;
    atomicAdd(&ss[j], lsum);
    atomicAdd(&sq[j], lsq);
    __syncthreads();
    if (t < 128) { atomicAdd(&s2[t], ss[t]); atomicAdd(&s2[128+t], sq[t]); }
}

// ---------------------------------------------------------------------------
// k_mlp2: h = bn2(h0); mlp = h @ W2 + b2; out0 = pos + mlp[:,:2];
//         out1 = x + mlp[:,2:]
// ---------------------------------------------------------------------------
__global__ __launch_bounds__(256) void k_mlp2(const float* __restrict__ h0,
                                              const float* __restrict__ x,
                                              const float* __restrict__ pos,
                                              const float* __restrict__ g2,
                                              const float* __restrict__ bt2,
                                              const float* __restrict__ W2,
                                              const float* __restrict__ b2,
                                              const float* __restrict__ s2,
                                              float* __restrict__ out) {
    __shared__ float red[4][64][34];
    int t = threadIdx.x;
    int lane = t & 63, w = t >> 6;
    int n = blockIdx.x*64 + lane;
    int j0 = w*32;
    float hv[32];
    #pragma unroll
    for (int q = 0; q < 8; ++q)
        *(float4*)&hv[q*4] = *(const float4*)&h0[(size_t)n*CMM + j0 + q*4];
    #pragma unroll
    for (int jj = 0; jj < 32; ++jj) {
        int j = j0 + jj;
        float mu  = s2[j] * (1.f/NTOT);
        float var = s2[128+j]*(1.f/NTOT) - mu*mu;
        float a   = g2[j] * rsqrtf(var + EPS);
        hv[jj] = a*(hv[jj] - mu) + bt2[j];
    }
    float acc[34];
    #pragma unroll
    for (int c = 0; c < 34; ++c) acc[c] = 0.f;
    for (int jj = 0; jj < 32; ++jj) {
        float h = hv[jj];
        const float* w2r = W2 + (size_t)(j0 + jj)*34;   // wave-uniform -> s_load
        #pragma unroll
        for (int c = 0; c < 34; ++c)
            acc[c] = fmaf(h, w2r[c], acc[c]);
    }
    #pragma unroll
    for (int c = 0; c < 34; ++c) red[w][lane][c] = acc[c];
    __syncthreads();
    int r = t & 63, seg = t >> 6;
    int c0 = seg*9, c1 = c0 + 9 < 34 ? c0 + 9 : 34;
    int nn = blockIdx.x*64 + r;
    for (int c = c0; c < c1; ++c) {
        float v = red[0][r][c] + red[1][r][c] + red[2][r][c] + red[3][r][c] + b2[c];
        if (c < 2)
            out[(size_t)nn*2 + c] = pos[(size_t)nn*2 + c] + v;
        else
            out[16384 + (size_t)nn*32 + (c-2)] = x[(size_t)nn*32 + (c-2)] + v;
    }
}

// ---------------------------------------------------------------------------
extern "C" void kernel_launch(void* const* d_in, const int* in_sizes, int n_in,
                              void* d_out, int out_size, void* d_ws, size_t ws_size,
                              hipStream_t stream) {
    const float* positions = (const float*)d_in[0];
    const float* weights   = (const float*)d_in[1];
    // d_in[2] = batch (int32) — unused, shapes static
    const float* kpos = (const float*)d_in[3];
    const float* kw   = (const float*)d_in[4];
    const float* cg   = (const float*)d_in[5];
    const float* cb   = (const float*)d_in[6];
    const float* W1   = (const float*)d_in[7];
    const float* b1   = (const float*)d_in[8];
    const float* bg   = (const float*)d_in[9];
    const float* bb   = (const float*)d_in[10];
    const float* W2   = (const float*)d_in[11];
    const float* b2   = (const float*)d_in[12];
    float* ws  = (float*)d_ws;
    float* out = (float*)d_out;

    hipMemsetAsync(ws + OFF_S1, 0, (64 + 256)*sizeof(float), stream);

    k_prep<<<(BB*MM + KK*CC*CC + 255)/256, 256, 0, stream>>>(
        positions, kpos, kw, ws + OFF_CFX, ws + OFF_CFY, ws + OFF_CF0, ws + OFF_KWT);
    k_convw<<<128, 256, 0, stream>>>(weights, ws + OFF_KWT, (short*)(ws + OFF_CWT));
    k_sample<<<512, 256, 0, stream>>>(positions, ws + OFF_CFX, ws + OFF_CFY,
                                      ws + OFF_CF0, (const short*)(ws + OFF_CWT),
                                      ws + OFF_PART);
    k_leaky_stats<<<128, 256, 0, stream>>>(ws + OFF_PART, ws + OFF_X0, ws + OFF_S1);
    k_mlp1<<<128, 256, 0, stream>>>(ws + OFF_X0, weights, cg, cb, W1, b1,
                                    ws + OFF_S1, ws + OFF_X, ws + OFF_H0);
    k_stats2<<<256, 256, 0, stream>>>(ws + OFF_H0, ws + OFF_S2);
    k_mlp2<<<128, 256, 0, stream>>>(ws + OFF_H0, ws + OFF_X, positions,
                                    bg, bb, W2, b2, ws + OFF_S2, out);
}

// Round 4
// 165.948 us; speedup vs baseline: 3.0796x; 1.2420x over previous
//
#include <hip/hip_runtime.h>
#include <hip/hip_bf16.h>

// Problem constants
#define BB    8
#define NBB   1024
#define KK    9
#define CC    32
#define CMM   128
#define NTOT  (BB*NBB)        // 8192
#define MM    (NBB*KK)        // 9216 per batch
#define MS    16              // K-split ways
#define MR    (MM/MS)         // 576 m per split
#define NEG   0.01f
#define EPS   1e-5f
#define L2C   (-2.8853900817779268f)   /* -2*log2(e) */

// Workspace layout (floats)
#define OFF_CWT   0
#define SZ_CWT    (BB*CC*MM/2)            // bf16 as float-slots: 1179648
#define OFF_CFX   (OFF_CWT + SZ_CWT)
#define OFF_CFY   (OFF_CFX + BB*MM)
#define OFF_CF0   (OFF_CFY + BB*MM)
#define OFF_PART  (OFF_CF0 + BB*MM)
#define SZ_ONE    (NTOT*CC)               // 262144
#define SZ_PART   (MS*SZ_ONE)
// aliases into dead partial slots (consumed by k_leaky_stats before reuse)
#define OFF_X0    (OFF_PART)              // slot 0 (same-thread RAW in k_leaky)
#define OFF_X     (OFF_PART + SZ_ONE)     // slot 1
#define OFF_H0    (OFF_PART + 2*SZ_ONE)   // slots 2..5
#define OFF_ST    (OFF_PART + SZ_PART)    // stats: s1[64] then s2[256]

typedef __attribute__((ext_vector_type(8))) short short8;
typedef __attribute__((ext_vector_type(4))) float f32x4;
typedef __attribute__((ext_vector_type(2))) float f32x2;

static __device__ __forceinline__ unsigned short f2bf_rne(float f) {
    __hip_bfloat16 h = __float2bfloat16(f);
    return *reinterpret_cast<unsigned short*>(&h);
}

// ---------------------------------------------------------------------------
// k_prep: per-m Gaussian coefs; block 0 also zeroes the stats accumulators.
//   q = pos[m/9] + kpos[m%9]
//   cfx = -2*L2C*qx, cfy = -2*L2C*qy, cf0 = L2C*|q|^2
//   E(n,m) = cn + cf0 + cfx*px + cfy*py, cn = L2C*|p|^2, e = exp2(E)
// ---------------------------------------------------------------------------
__global__ __launch_bounds__(256) void k_prep(const float* __restrict__ pos,
                                              const float* __restrict__ kpos,
                                              float* __restrict__ cfx,
                                              float* __restrict__ cfy,
                                              float* __restrict__ cf0,
                                              float* __restrict__ stats) {
    int gid = blockIdx.x*256 + threadIdx.x;
    if (blockIdx.x == 0 && threadIdx.x < 320) stats[threadIdx.x] = 0.f;
    if (gid < BB*MM) {
        int b = gid / MM;
        int m = gid - b*MM;
        int np = m / 9, k9 = m - np*9;
        float qx = pos[((size_t)(b*NBB + np))*2 + 0] + kpos[k9*2 + 0];
        float qy = pos[((size_t)(b*NBB + np))*2 + 1] + kpos[k9*2 + 1];
        cfx[gid] = -2.f*L2C*qx;
        cfy[gid] = -2.f*L2C*qy;
        cf0[gid] = L2C*(qx*qx + qy*qy);
    }
}

// ---------------------------------------------------------------------------
// k_convw (MFMA): cwT[b][c][m] bf16, m = nloc*9+k,
//   conv_w[n][k][c] = sum_cp w[n][cp] * kw[k][cp][c]
// Per k: D[c][n] = kwT_k(32x32) x wT(32xN). A-frag: kw gathered (L1-hot),
// B-frag: w rows contiguous. D -> per-wave LDS tile -> coalesced bf16 out.
// grid = 128 (8 b x 16 nblk of 64 n); wave = 16 n.
// ---------------------------------------------------------------------------
__global__ __launch_bounds__(256) void k_convw(const float* __restrict__ w,
                                               const float* __restrict__ kw,
                                               short* __restrict__ cwT) {
    __shared__ unsigned short tile[4*32*144];   // 36 KB, per-wave tiles
    int t = threadIdx.x;
    int l = t & 63, wv = t >> 6;
    int lane15 = l & 15, quad = l >> 4;
    int blk = blockIdx.x;
    int b = blk >> 4, nbl = blk & 15;
    int n = b*NBB + nbl*64 + wv*16 + lane15;

    // B-frag: w[n][quad*8 .. +7] -> bf16
    f32x4 w0 = *(const f32x4*)&w[(size_t)n*CC + quad*8];
    f32x4 w1 = *(const f32x4*)&w[(size_t)n*CC + quad*8 + 4];
    union { unsigned short us[8]; short8 s; } bfr;
    bfr.us[0] = f2bf_rne(w0.x); bfr.us[1] = f2bf_rne(w0.y);
    bfr.us[2] = f2bf_rne(w0.z); bfr.us[3] = f2bf_rne(w0.w);
    bfr.us[4] = f2bf_rne(w1.x); bfr.us[5] = f2bf_rne(w1.y);
    bfr.us[6] = f2bf_rne(w1.z); bfr.us[7] = f2bf_rne(w1.w);

    f32x4 acc[KK][2];
    #pragma unroll
    for (int kk = 0; kk < KK; ++kk) {
        #pragma unroll
        for (int ct = 0; ct < 2; ++ct) {
            int c = ct*16 + lane15;
            union { unsigned short us[8]; short8 s; } afr;
            #pragma unroll
            for (int j = 0; j < 8; ++j)
                afr.us[j] = f2bf_rne(kw[(size_t)(kk*CC + quad*8 + j)*CC + c]);
            acc[kk][ct] = __builtin_amdgcn_mfma_f32_16x16x32_bf16(
                afr.s, bfr.s, (f32x4)0.f, 0, 0, 0);
        }
    }
    // D: col(n)=lane15, row(c)=quad*4+reg. Stash to per-wave LDS tile [c][nloc*9+k]
    unsigned short* tw = tile + wv*4608;
    #pragma unroll
    for (int kk = 0; kk < KK; ++kk)
        #pragma unroll
        for (int ct = 0; ct < 2; ++ct)
            #pragma unroll
            for (int reg = 0; reg < 4; ++reg) {
                int c = ct*16 + quad*4 + reg;
                tw[c*144 + lane15*9 + kk] = f2bf_rne(acc[kk][ct][reg]);
            }
    __syncthreads();
    // coalesced writeout: 9 insts x 64 lanes covering 32 c x 144 m (per wave)
    short* dst = cwT + (size_t)b*CC*MM + (size_t)(nbl*64 + wv*16)*9;
    #pragma unroll
    for (int it = 0; it < 9; ++it) {
        int u = it*64 + l;
        int c = u / 18, seg = u - c*18;
        short8 v = *(const short8*)&tw[c*144 + seg*8];
        *(short8*)&dst[(size_t)c*MM + seg*8] = v;
    }
}

// ---------------------------------------------------------------------------
// k_sample (dominant, MFMA): part[ks][n][c] = sum_{m} exp2(E) * conv_w[m][c]
// M=c, N=n, K=m. A from cwT global (L1-shared), B = e in registers. NO LDS.
// grid = 8 b x 8 nblk(128 n) x 16 ksplit = 1024 blocks; wave = 2 n-tiles.
// ---------------------------------------------------------------------------
__global__ __launch_bounds__(256) void k_sample(const float* __restrict__ pos,
                                                const float* __restrict__ cfx,
                                                const float* __restrict__ cfy,
                                                const float* __restrict__ cf0,
                                                const short* __restrict__ cwT,
                                                float* __restrict__ part) {
    int t = threadIdx.x;
    int l = t & 63, w = t >> 6;
    int blk = blockIdx.x;
    int ks = blk & 15, nb = (blk >> 4) & 7, b = blk >> 7;
    int lane15 = l & 15, quad = l >> 4;
    int nbase = b*NBB + nb*128 + w*32;

    float px[2], py[2], cn[2];
    #pragma unroll
    for (int nt = 0; nt < 2; ++nt) {
        int n = nbase + nt*16 + lane15;
        float x = pos[(size_t)n*2], y = pos[(size_t)n*2 + 1];
        px[nt] = x; py[nt] = y; cn[nt] = L2C*(x*x + y*y);
    }
    f32x4 acc[2][2];
    #pragma unroll
    for (int nt = 0; nt < 2; ++nt) { acc[nt][0] = (f32x4)0.f; acc[nt][1] = (f32x4)0.f; }

    const float* bx = cfx + (size_t)b*MM;
    const float* by = cfy + (size_t)b*MM;
    const float* b0 = cf0 + (size_t)b*MM;
    const short* ca0 = cwT + (size_t)b*CC*MM + (size_t)lane15*MM;
    const short* ca1 = ca0 + (size_t)16*MM;

    int m0 = ks*MR + quad*8;
    #pragma unroll 2
    for (int kk = 0; kk < MR/32; ++kk, m0 += 32) {
        short8 a0 = *(const short8*)&ca0[m0];
        short8 a1 = *(const short8*)&ca1[m0];
        f32x4 vx0 = *(const f32x4*)&bx[m0];
        f32x4 vx1 = *(const f32x4*)&bx[m0 + 4];
        f32x4 vy0 = *(const f32x4*)&by[m0];
        f32x4 vy1 = *(const f32x4*)&by[m0 + 4];
        f32x4 v00 = *(const f32x4*)&b0[m0];
        f32x4 v01 = *(const f32x4*)&b0[m0 + 4];
        #pragma unroll
        for (int nt = 0; nt < 2; ++nt) {
            f32x2 Xv = {px[nt], px[nt]};
            f32x2 Yv = {py[nt], py[nt]};
            f32x2 Cv = {cn[nt], cn[nt]};
            // E pairs via packed fma (v_pk_fma_f32)
            f32x2 t0 = (f32x2){v00.x, v00.y} + Cv;
            t0 = (f32x2){vy0.x, vy0.y}*Yv + t0;
            t0 = (f32x2){vx0.x, vx0.y}*Xv + t0;
            f32x2 t1 = (f32x2){v00.z, v00.w} + Cv;
            t1 = (f32x2){vy0.z, vy0.w}*Yv + t1;
            t1 = (f32x2){vx0.z, vx0.w}*Xv + t1;
            f32x2 t2 = (f32x2){v01.x, v01.y} + Cv;
            t2 = (f32x2){vy1.x, vy1.y}*Yv + t2;
            t2 = (f32x2){vx1.x, vx1.y}*Xv + t2;
            f32x2 t3 = (f32x2){v01.z, v01.w} + Cv;
            t3 = (f32x2){vy1.z, vy1.w}*Yv + t3;
            t3 = (f32x2){vx1.z, vx1.w}*Xv + t3;
            float e0 = __builtin_amdgcn_exp2f(t0.x);
            float e1 = __builtin_amdgcn_exp2f(t0.y);
            float e2 = __builtin_amdgcn_exp2f(t1.x);
            float e3 = __builtin_amdgcn_exp2f(t1.y);
            float e4 = __builtin_amdgcn_exp2f(t2.x);
            float e5 = __builtin_amdgcn_exp2f(t2.y);
            float e6 = __builtin_amdgcn_exp2f(t3.x);
            float e7 = __builtin_amdgcn_exp2f(t3.y);
            union { unsigned int u[4]; short8 s; } bf;
            bf.u[0] = (__float_as_uint(e0) >> 16) | (__float_as_uint(e1) & 0xffff0000u);
            bf.u[1] = (__float_as_uint(e2) >> 16) | (__float_as_uint(e3) & 0xffff0000u);
            bf.u[2] = (__float_as_uint(e4) >> 16) | (__float_as_uint(e5) & 0xffff0000u);
            bf.u[3] = (__float_as_uint(e6) >> 16) | (__float_as_uint(e7) & 0xffff0000u);
            acc[nt][0] = __builtin_amdgcn_mfma_f32_16x16x32_bf16(a0, bf.s, acc[nt][0], 0, 0, 0);
            acc[nt][1] = __builtin_amdgcn_mfma_f32_16x16x32_bf16(a1, bf.s, acc[nt][1], 0, 0, 0);
        }
    }
    // D: col(n)=lane15, row(c)=quad*4+reg
    #pragma unroll
    for (int nt = 0; nt < 2; ++nt) {
        int n = nbase + nt*16 + lane15;
        #pragma unroll
        for (int ct = 0; ct < 2; ++ct) {
            int c = ct*16 + quad*4;
            *(f32x4*)&part[((size_t)ks*NTOT + n)*CC + c] = acc[nt][ct];
        }
    }
}

// ---------------------------------------------------------------------------
// k_leaky_stats: x0 = leaky(sum of 16 partials); accumulate bn1 sum/sumsq
// ---------------------------------------------------------------------------
__global__ __launch_bounds__(256) void k_leaky_stats(const float* __restrict__ part,
                                                     float* __restrict__ x0,
                                                     float* __restrict__ s1) {
    __shared__ float ss[32], sq[32];
    int t = threadIdx.x;
    if (t < 32) { ss[t] = 0.f; sq[t] = 0.f; }
    __syncthreads();
    float lsum = 0.f, lsq = 0.f;
    int base = blockIdx.x * 1024;
    for (int j = 0; j < 4; ++j) {
        int idx = base + j*256 + t;
        float v = 0.f;
        #pragma unroll
        for (int s = 0; s < MS; ++s) v += part[(size_t)s*SZ_ONE + idx];
        v = v >= 0.f ? v : NEG*v;
        x0[idx] = v;   // aliases partial slot 0: same-thread read-then-write
        lsum += v; lsq = fmaf(v, v, lsq);
    }
    atomicAdd(&ss[t & 31], lsum);
    atomicAdd(&sq[t & 31], lsq);
    __syncthreads();
    if (t < 32) { atomicAdd(&s1[t], ss[t]); atomicAdd(&s1[32+t], sq[t]); }
}

// ---------------------------------------------------------------------------
// k_mlp1: x = bn1(x0) + weights; h0 = leaky(x @ W1 + b1); fused bn2 stats.
// grid = 256: block = 64 n x 64 j (j-half). W1 rows via wave-uniform s_load.
// Stats: LDS transpose [j][n] -> 4-lane partial sums -> global atomics.
// ---------------------------------------------------------------------------
__global__ __launch_bounds__(256) void k_mlp1(const float* __restrict__ x0,
                                              const float* __restrict__ wts,
                                              const float* __restrict__ gma,
                                              const float* __restrict__ bta,
                                              const float* __restrict__ W1,
                                              const float* __restrict__ b1,
                                              const float* __restrict__ s1,
                                              float* __restrict__ x,
                                              float* __restrict__ h0,
                                              float* __restrict__ s2) {
    __shared__ float tile[64*68];   // [j_local][n] padded
    int t = threadIdx.x;
    int l = t & 63, w = t >> 6;
    int blk = blockIdx.x;
    int nb = blk >> 1, jh = blk & 1;
    int n = nb*64 + l;
    int j0 = jh*64 + w*16;

    float xv[32];
    #pragma unroll
    for (int c = 0; c < 32; ++c) {
        float mu  = s1[c] * (1.f/NTOT);
        float var = s1[32+c]*(1.f/NTOT) - mu*mu;
        float a   = gma[c] * rsqrtf(var + EPS);
        float v   = x0[(size_t)n*CC + c];
        xv[c] = a*(v - mu) + bta[c] + wts[(size_t)n*CC + c];
    }
    if (jh == 0 && w == 0) {
        #pragma unroll
        for (int c = 0; c < 32; c += 4)
            *(float4*)&x[(size_t)n*CC + c] = make_float4(xv[c], xv[c+1], xv[c+2], xv[c+3]);
    }
    float acc[16];
    #pragma unroll
    for (int jj = 0; jj < 16; ++jj) acc[jj] = b1[j0 + jj];
    #pragma unroll 4
    for (int c = 0; c < 32; ++c) {
        float xc = xv[c];
        const float* w1r = W1 + c*CMM + j0;   // wave-uniform -> s_load
        #pragma unroll
        for (int jj = 0; jj < 16; ++jj)
            acc[jj] = fmaf(xc, w1r[jj], acc[jj]);
    }
    float* hd = h0 + (size_t)n*CMM + j0;
    #pragma unroll
    for (int jj = 0; jj < 16; ++jj) {
        acc[jj] = acc[jj] >= 0.f ? acc[jj] : NEG*acc[jj];
        tile[(w*16 + jj)*68 + l] = acc[jj];
    }
    #pragma unroll
    for (int jj = 0; jj < 16; jj += 4)
        *(float4*)&hd[jj] = make_float4(acc[jj], acc[jj+1], acc[jj+2], acc[jj+3]);
    __syncthreads();
    // stats: thread -> (j_local = t>>2, grp = t&3), sum 16 n's each
    int jl = t >> 2, grp = t & 3;
    float lsum = 0.f, lsq = 0.f;
    #pragma unroll
    for (int q = 0; q < 4; ++q) {
        f32x4 v = *(const f32x4*)&tile[jl*68 + grp*16 + q*4];
        lsum += v.x + v.y + v.z + v.w;
        lsq = fmaf(v.x, v.x, fmaf(v.y, v.y, fmaf(v.z, v.z, fmaf(v.w, v.w, lsq))));
    }
    lsum += __shfl_xor(lsum, 1); lsq += __shfl_xor(lsq, 1);
    lsum += __shfl_xor(lsum, 2); lsq += __shfl_xor(lsq, 2);
    if (grp == 0) {
        int jg = jh*64 + jl;
        atomicAdd(&s2[jg], lsum);
        atomicAdd(&s2[CMM + jg], lsq);
    }
}

// ---------------------------------------------------------------------------
// k_mlp2: h = bn2(h0); mlp = h @ W2 + b2; out0 = pos + mlp[:,:2];
//         out1 = x + mlp[:,2:]
// ---------------------------------------------------------------------------
__global__ __launch_bounds__(256) void k_mlp2(const float* __restrict__ h0,
                                              const float* __restrict__ x,
                                              const float* __restrict__ pos,
                                              const float* __restrict__ g2,
                                              const float* __restrict__ bt2,
                                              const float* __restrict__ W2,
                                              const float* __restrict__ b2,
                                              const float* __restrict__ s2,
                                              float* __restrict__ out) {
    __shared__ float red[4][64][34];
    int t = threadIdx.x;
    int lane = t & 63, w = t >> 6;
    int n = blockIdx.x*64 + lane;
    int j0 = w*32;
    float hv[32];
    #pragma unroll
    for (int q = 0; q < 8; ++q)
        *(float4*)&hv[q*4] = *(const float4*)&h0[(size_t)n*CMM + j0 + q*4];
    #pragma unroll
    for (int jj = 0; jj < 32; ++jj) {
        int j = j0 + jj;
        float mu  = s2[j] * (1.f/NTOT);
        float var = s2[CMM+j]*(1.f/NTOT) - mu*mu;
        float a   = g2[j] * rsqrtf(var + EPS);
        hv[jj] = a*(hv[jj] - mu) + bt2[j];
    }
    float acc[34];
    #pragma unroll
    for (int c = 0; c < 34; ++c) acc[c] = 0.f;
    for (int jj = 0; jj < 32; ++jj) {
        float h = hv[jj];
        const float* w2r = W2 + (size_t)(j0 + jj)*34;   // wave-uniform -> s_load
        #pragma unroll
        for (int c = 0; c < 34; ++c)
            acc[c] = fmaf(h, w2r[c], acc[c]);
    }
    #pragma unroll
    for (int c = 0; c < 34; ++c) red[w][lane][c] = acc[c];
    __syncthreads();
    int r = t & 63, seg = t >> 6;
    int c0 = seg*9, c1 = c0 + 9 < 34 ? c0 + 9 : 34;
    int nn = blockIdx.x*64 + r;
    for (int c = c0; c < c1; ++c) {
        float v = red[0][r][c] + red[1][r][c] + red[2][r][c] + red[3][r][c] + b2[c];
        if (c < 2)
            out[(size_t)nn*2 + c] = pos[(size_t)nn*2 + c] + v;
        else
            out[16384 + (size_t)nn*32 + (c-2)] = x[(size_t)nn*32 + (c-2)] + v;
    }
}

// ---------------------------------------------------------------------------
extern "C" void kernel_launch(void* const* d_in, const int* in_sizes, int n_in,
                              void* d_out, int out_size, void* d_ws, size_t ws_size,
                              hipStream_t stream) {
    const float* positions = (const float*)d_in[0];
    const float* weights   = (const float*)d_in[1];
    // d_in[2] = batch (int32) — unused, shapes static
    const float* kpos = (const float*)d_in[3];
    const float* kw   = (const float*)d_in[4];
    const float* cg   = (const float*)d_in[5];
    const float* cb   = (const float*)d_in[6];
    const float* W1   = (const float*)d_in[7];
    const float* b1   = (const float*)d_in[8];
    const float* bg   = (const float*)d_in[9];
    const float* bb   = (const float*)d_in[10];
    const float* W2   = (const float*)d_in[11];
    const float* b2   = (const float*)d_in[12];
    float* ws  = (float*)d_ws;
    float* out = (float*)d_out;

    float* s1 = ws + OFF_ST;        // 64 floats
    float* s2 = ws + OFF_ST + 64;   // 256 floats

    k_prep<<<288, 256, 0, stream>>>(positions, kpos, ws + OFF_CFX, ws + OFF_CFY,
                                    ws + OFF_CF0, s1);
    k_convw<<<128, 256, 0, stream>>>(weights, kw, (short*)(ws + OFF_CWT));
    k_sample<<<1024, 256, 0, stream>>>(positions, ws + OFF_CFX, ws + OFF_CFY,
                                       ws + OFF_CF0, (const short*)(ws + OFF_CWT),
                                       ws + OFF_PART);
    k_leaky_stats<<<256, 256, 0, stream>>>(ws + OFF_PART, ws + OFF_X0, s1);
    k_mlp1<<<256, 256, 0, stream>>>(ws + OFF_X0, weights, cg, cb, W1, b1,
                                    s1, ws + OFF_X, ws + OFF_H0, s2);
    k_mlp2<<<128, 256, 0, stream>>>(ws + OFF_H0, ws + OFF_X, positions,
                                    bg, bb, W2, b2, s2, out);
}